// Round 4
// baseline (150.630 us; speedup 1.0000x reference)
//
#include <hip/hip_runtime.h>

// Problem constants
// B=32, T_IN=12, H=64, W=64, C_IN=4, T_OUT=12, C_OUT=4, O=48, K=8, S=4
// NH=NW=15, L=225. DEC_K=25, p=12 -> trend[t] = A + t*D (affine in t).

// Packed weights: PW[(s*48 + o)*64 + k], s = i*8 + j, k in [0,57):
//   k=t*4+c  (0..47): w_s[o,t,c,i,j]
//   k=48+c          : W0[o,c,i,j] = sum_t (w_t - w_s)
//   k=52+c          : W1[o,c,i,j] = sum_t t*(w_t - w_s)
//   k=56            : b_s[o,i,j] + b_t[o,i,j]
// One block per o (48 blocks), 64 threads = s. All w reads coalesced
// (s is the innermost, contiguous dim of (O,T,C,K,K)).
__global__ __launch_bounds__(64) void pack_weights(const float* __restrict__ w_s,
                                                   const float* __restrict__ b_s,
                                                   const float* __restrict__ w_t,
                                                   const float* __restrict__ b_t,
                                                   float* __restrict__ PW) {
    int o = blockIdx.x;   // 0..47
    int s = threadIdx.x;  // 0..63
    float* dst = PW + (size_t)(s * 48 + o) * 64;
    float w0[4] = {0.f, 0.f, 0.f, 0.f};
    float w1[4] = {0.f, 0.f, 0.f, 0.f};
#pragma unroll
    for (int t = 0; t < 12; ++t) {
#pragma unroll
        for (int c = 0; c < 4; ++c) {
            int wi = ((o * 12 + t) * 4 + c) * 64 + s;
            float ws = w_s[wi];
            float wt = w_t[wi];
            dst[t * 4 + c] = ws;
            float d = wt - ws;
            w0[c] += d;
            w1[c] += (float)t * d;
        }
    }
#pragma unroll
    for (int c = 0; c < 4; ++c) {
        dst[48 + c] = w0[c];
        dst[52 + c] = w1[c];
    }
    dst[56] = b_s[o * 64 + s] + b_t[o * 64 + s];
}

// Grid: 32 b x 16 residue classes x 3 to-groups = 1536 blocks = 6 blocks/CU.
// __launch_bounds__(256,6): unified VGPR+AGPR cap ~85 -> steady state
// (X[57] + 4 acc + working ~76) fits without scratch spill; 24 waves/CU
// (75% occupancy) to hide the s_load weight-stream latency, which round-3
// counters showed is the limiter (VALUBusy 28% @ 39% occupancy).
// Each block: 256 threads = 16x16 pixels of one residue class, 4 of the 12
// output timesteps. Thread: load x[12][4] once (float4/t), build
// X[57] = [x(t,c), A(c), D(c), 1], dot against <=4 wave-uniform (scalar-load)
// packed weight slices per to.
__global__ __launch_bounds__(256, 6) void dlinear_main(const float* __restrict__ x,
                                                       const float* __restrict__ PW,
                                                       float* __restrict__ out) {
    int tid = threadIdx.x;
    int hh = tid >> 4;  // 0..15
    int ww = tid & 15;  // 0..15
    unsigned bx = blockIdx.x;
    int tg = bx % 3;           // to-group: to = 4*tg .. 4*tg+3
    unsigned rest = bx / 3;    // 0..511
    int cls = rest & 15;       // residue class
    int bb = rest >> 4;        // batch
    int rh = cls >> 2;  // h residue 0..3
    int rw = cls & 3;   // w residue 0..3
    int h = 4 * hh + rh;
    int w = 4 * ww + rw;

    // x layout (B,T,H,W,C): float4 index = (b*12+t)*4096 + h*64 + w
    const float4* xb = (const float4*)x + (size_t)bb * 12 * 4096 + h * 64 + w;

    float X[57];
    float sx = 0.f, sy = 0.f, sz = 0.f, sw = 0.f;
#pragma unroll
    for (int t = 0; t < 12; ++t) {
        float4 v = xb[t * 4096];
        X[t * 4 + 0] = v.x;
        X[t * 4 + 1] = v.y;
        X[t * 4 + 2] = v.z;
        X[t * 4 + 3] = v.w;
        sx += v.x; sy += v.y; sz += v.z; sw += v.w;
    }
    const float inv25 = 1.0f / 25.0f;
    {
        float S[4] = {sx, sy, sz, sw};
#pragma unroll
        for (int c = 0; c < 4; ++c) {
            float x0 = X[c], x11 = X[44 + c];
            X[48 + c] = (S[c] + 12.f * x0 + x11) * inv25;  // A
            X[52 + c] = (x11 - x0) * inv25;                // D
        }
    }
    X[56] = 1.0f;

    // combo validity: di=0 needs hh<=14; di=1 needs hh>=1 (same for j/ww)
    bool iv[2] = {hh <= 14, hh >= 1};
    bool jv[2] = {ww <= 14, ww >= 1};

    float4* ob = (float4*)out + (size_t)bb * 12 * 4096 + h * 64 + w;

#pragma unroll
    for (int tt = 0; tt < 4; ++tt) {
        int to = 4 * tg + tt;
        float rx = 0.f, ry = 0.f, rz = 0.f, rw4 = 0.f;
#pragma unroll
        for (int di = 0; di < 2; ++di) {
#pragma unroll
            for (int dj = 0; dj < 2; ++dj) {
                if (iv[di] && jv[dj]) {
                    int s = (rh + 4 * di) * 8 + (rw + 4 * dj);
                    const float* wb = PW + (size_t)(s * 48 + to * 4) * 64;
                    float a0 = 0.f, a1 = 0.f, a2 = 0.f, a3 = 0.f;
#pragma unroll
                    for (int k = 0; k < 57; ++k) {
                        float xv = X[k];
                        a0 += xv * wb[k];
                        a1 += xv * wb[64 + k];
                        a2 += xv * wb[128 + k];
                        a3 += xv * wb[192 + k];
                    }
                    rx += a0; ry += a1; rz += a2; rw4 += a3;
                }
            }
        }
        float4 r;
        r.x = rx; r.y = ry; r.z = rz; r.w = rw4;
        ob[to * 4096] = r;
    }
}

extern "C" void kernel_launch(void* const* d_in, const int* in_sizes, int n_in,
                              void* d_out, int out_size, void* d_ws, size_t ws_size,
                              hipStream_t stream) {
    const float* x = (const float*)d_in[0];
    const float* w_s = (const float*)d_in[1];
    const float* b_s = (const float*)d_in[2];
    const float* w_t = (const float*)d_in[3];
    const float* b_t = (const float*)d_in[4];
    float* out = (float*)d_out;
    float* PW = (float*)d_ws;  // needs 48*64*64*4 = 786432 bytes

    pack_weights<<<48, 64, 0, stream>>>(w_s, b_s, w_t, b_t, PW);
    dlinear_main<<<32 * 16 * 3, 256, 0, stream>>>(x, PW, out);
}

// Round 5
// 127.114 us; speedup vs baseline: 1.1850x; 1.1850x over previous
//
#include <hip/hip_runtime.h>

// Problem constants
// B=32, T_IN=12, H=64, W=64, C_IN=4, T_OUT=12, C_OUT=4, O=48, K=8, S=4
// NH=NW=15, L=225. DEC_K=25, p=12 -> trend[t] = A + t*D (affine in t).
//
// f16 pair formulation: X2[29] half2 pairs per pixel:
//   p=0..23 : (x[t,c0],x[t,c1]) pairs, t=p>>1, c0=(p&1)*2
//   p=24,25 : A[0..3]   (trend intercept per c)
//   p=26,27 : D[0..3]   (trend slope per c)
//   p=28    : (1.0, 0)  (bias)
// Weights PW2[(s*48+o)*32 + p] packed to match (s=i*8+j, o=to*4+c_out):
//   p<24: w_s pairs; 24..27: W0=sum_t(w_t-w_s), W1=sum_t t*(w_t-w_s); 28:(bias,0)

typedef _Float16 h2 __attribute__((ext_vector_type(2)));
union H2U { h2 h; unsigned u; };

#if __has_builtin(__builtin_amdgcn_fdot2)
__device__ inline float fdot2(h2 a, h2 b, float c) {
    return __builtin_amdgcn_fdot2(a, b, c, false);
}
#else
__device__ inline float fdot2(h2 a, h2 b, float c) {
    return c + (float)a[0] * (float)b[0] + (float)a[1] * (float)b[1];
}
#endif

// One block per o (48), 64 threads = s (coalesced: s innermost in (O,T,C,K,K)).
__global__ __launch_bounds__(64) void pack_weights(const float* __restrict__ w_s,
                                                   const float* __restrict__ b_s,
                                                   const float* __restrict__ w_t,
                                                   const float* __restrict__ b_t,
                                                   unsigned* __restrict__ PW2) {
    int o = blockIdx.x;   // 0..47
    int s = threadIdx.x;  // 0..63
    unsigned* dst = PW2 + (size_t)(s * 48 + o) * 32;
    float wsv[48];
    float w0[4] = {0.f, 0.f, 0.f, 0.f};
    float w1[4] = {0.f, 0.f, 0.f, 0.f};
#pragma unroll
    for (int t = 0; t < 12; ++t) {
#pragma unroll
        for (int c = 0; c < 4; ++c) {
            int wi = ((o * 12 + t) * 4 + c) * 64 + s;
            float ws = w_s[wi];
            float wt = w_t[wi];
            wsv[t * 4 + c] = ws;
            float d = wt - ws;
            w0[c] += d;
            w1[c] += (float)t * d;
        }
    }
#pragma unroll
    for (int p = 0; p < 24; ++p) {
        H2U u;
        u.h[0] = (_Float16)wsv[2 * p];
        u.h[1] = (_Float16)wsv[2 * p + 1];
        dst[p] = u.u;
    }
    H2U u;
    u.h[0] = (_Float16)w0[0]; u.h[1] = (_Float16)w0[1]; dst[24] = u.u;
    u.h[0] = (_Float16)w0[2]; u.h[1] = (_Float16)w0[3]; dst[25] = u.u;
    u.h[0] = (_Float16)w1[0]; u.h[1] = (_Float16)w1[1]; dst[26] = u.u;
    u.h[0] = (_Float16)w1[2]; u.h[1] = (_Float16)w1[3]; dst[27] = u.u;
    float bias = b_s[o * 64 + s] + b_t[o * 64 + s];
    u.h[0] = (_Float16)bias; u.h[1] = (_Float16)0.f; dst[28] = u.u;
    dst[29] = 0u; dst[30] = 0u; dst[31] = 0u;
}

// Grid: 16 b-pairs x 16 residue classes x 4 to-groups = 1024 blocks (4/CU).
// Each thread: 2 pixels (batch bp and bp+16, same (h,w)), 3 output timesteps.
// Per weight dword (2 f16) we now do 2 fdot2 (one per pixel) -> 2x FMA work
// per scalar byte, and per-CU scalar traffic drops to ~24 KB (was 96 KB in
// r3/r4, which the counters showed was the serialized bottleneck).
__global__ __launch_bounds__(256, 4) void dlinear_main(const float* __restrict__ x,
                                                       const unsigned* __restrict__ PW2,
                                                       float* __restrict__ out) {
    int tid = threadIdx.x;
    int hh = tid >> 4;  // 0..15
    int ww = tid & 15;  // 0..15
    unsigned bx = blockIdx.x;
    int tg = bx & 3;            // to-group: to = 3*tg .. 3*tg+2
    int cls = (bx >> 2) & 15;   // residue class
    int bp = bx >> 6;           // batch pair: b0=bp, b1=bp+16
    int rh = cls >> 2;
    int rw = cls & 3;
    int h = 4 * hh + rh;
    int w = 4 * ww + rw;

    const float4* xb0 = (const float4*)x + (size_t)bp * 12 * 4096 + h * 64 + w;
    const float4* xb1 = xb0 + (size_t)16 * 12 * 4096;

    h2 X0[29], X1[29];
    const float inv25 = 1.0f / 25.0f;
#pragma unroll
    for (int q = 0; q < 2; ++q) {
        const float4* xb = q ? xb1 : xb0;
        h2* X = q ? X1 : X0;
        float sx = 0.f, sy = 0.f, sz = 0.f, sw = 0.f;
        float4 first, last;
#pragma unroll
        for (int t = 0; t < 12; ++t) {
            float4 v = xb[t * 4096];
            if (t == 0) first = v;
            if (t == 11) last = v;
            h2 a, b;
            a[0] = (_Float16)v.x; a[1] = (_Float16)v.y;
            b[0] = (_Float16)v.z; b[1] = (_Float16)v.w;
            X[2 * t] = a;
            X[2 * t + 1] = b;
            sx += v.x; sy += v.y; sz += v.z; sw += v.w;
        }
        float A0 = (sx + 12.f * first.x + last.x) * inv25;
        float A1 = (sy + 12.f * first.y + last.y) * inv25;
        float A2 = (sz + 12.f * first.z + last.z) * inv25;
        float A3 = (sw + 12.f * first.w + last.w) * inv25;
        float D0 = (last.x - first.x) * inv25;
        float D1 = (last.y - first.y) * inv25;
        float D2 = (last.z - first.z) * inv25;
        float D3 = (last.w - first.w) * inv25;
        h2 t0, t1, t2, t3, t4;
        t0[0] = (_Float16)A0; t0[1] = (_Float16)A1;
        t1[0] = (_Float16)A2; t1[1] = (_Float16)A3;
        t2[0] = (_Float16)D0; t2[1] = (_Float16)D1;
        t3[0] = (_Float16)D2; t3[1] = (_Float16)D3;
        t4[0] = (_Float16)1.f; t4[1] = (_Float16)0.f;
        X[24] = t0; X[25] = t1; X[26] = t2; X[27] = t3; X[28] = t4;
    }

    // combo validity: di=0 needs hh<=14; di=1 needs hh>=1 (same for j/ww)
    bool iv[2] = {hh <= 14, hh >= 1};
    bool jv[2] = {ww <= 14, ww >= 1};

    float4* ob0 = (float4*)out + (size_t)bp * 12 * 4096 + h * 64 + w;
    float4* ob1 = ob0 + (size_t)16 * 12 * 4096;

#pragma unroll 1
    for (int tt = 0; tt < 3; ++tt) {
        int to = 3 * tg + tt;
        float a0[4] = {0.f, 0.f, 0.f, 0.f};
        float a1[4] = {0.f, 0.f, 0.f, 0.f};
#pragma unroll
        for (int di = 0; di < 2; ++di) {
#pragma unroll
            for (int dj = 0; dj < 2; ++dj) {
                if (iv[di] && jv[dj]) {
                    int s = (rh + 4 * di) * 8 + (rw + 4 * dj);
                    const unsigned* wb = PW2 + (size_t)(s * 48 + to * 4) * 32;
#pragma unroll
                    for (int o = 0; o < 4; ++o) {
                        float c0 = a0[o], c1 = a1[o];
#pragma unroll
                        for (int p = 0; p < 29; ++p) {
                            H2U u;
                            u.u = wb[o * 32 + p];
                            c0 = fdot2(X0[p], u.h, c0);
                            c1 = fdot2(X1[p], u.h, c1);
                        }
                        a0[o] = c0; a1[o] = c1;
                    }
                }
            }
        }
        float4 r0, r1;
        r0.x = a0[0]; r0.y = a0[1]; r0.z = a0[2]; r0.w = a0[3];
        r1.x = a1[0]; r1.y = a1[1]; r1.z = a1[2]; r1.w = a1[3];
        ob0[to * 4096] = r0;
        ob1[to * 4096] = r1;
    }
}

extern "C" void kernel_launch(void* const* d_in, const int* in_sizes, int n_in,
                              void* d_out, int out_size, void* d_ws, size_t ws_size,
                              hipStream_t stream) {
    const float* x = (const float*)d_in[0];
    const float* w_s = (const float*)d_in[1];
    const float* b_s = (const float*)d_in[2];
    const float* w_t = (const float*)d_in[3];
    const float* b_t = (const float*)d_in[4];
    float* out = (float*)d_out;
    unsigned* PW2 = (unsigned*)d_ws;  // 48*64*32*4 = 393216 bytes

    pack_weights<<<48, 64, 0, stream>>>(w_s, b_s, w_t, b_t, PW2);
    dlinear_main<<<16 * 16 * 4, 256, 0, stream>>>(x, PW2, out);
}

// Round 6
// 111.650 us; speedup vs baseline: 1.3491x; 1.1385x over previous
//
#include <hip/hip_runtime.h>

// B=32, T_IN=12, H=64, W=64, C_IN=4, T_OUT=12, C_OUT=4, O=48, K=8, S=4
// NH=NW=15, L=225. DEC_K=25, p=12 -> trend[t] = A + t*D (affine in t).
//
// Per (batch, residue class (rh,rw)) block, the whole problem is a GEMM:
//   A = X[256 pixels x 64]   (K=57 used: x(t,c) 0..47, A(c) 48..51, D(c) 52..55, 1 @56)
//   B = W_cls[64 x 192]      (N = to*16 + c*4 + combo;  combo r: di=r>>1, dj=r&1,
//                             s = (rh+4di)*8 + (rw+4dj))
// then a masked 4-combo reduce per pixel (fold edges) and scatter-store.

typedef _Float16 h2 __attribute__((ext_vector_type(2)));
typedef _Float16 f16x8 __attribute__((ext_vector_type(8)));
typedef float f32x4 __attribute__((ext_vector_type(4)));
union F4F16 { float4 f4; f16x8 h8; };

// ---- pack1: PW[(s*48+o)*64 + k] f32, k: 0..47 w_s(t,c), 48..51 W0, 52..55 W1,
//      56 bias, 57..63 zero. One block per o, 64 threads = s (coalesced reads).
__global__ __launch_bounds__(64) void pack_weights(const float* __restrict__ w_s,
                                                   const float* __restrict__ b_s,
                                                   const float* __restrict__ w_t,
                                                   const float* __restrict__ b_t,
                                                   float* __restrict__ PW) {
    int o = blockIdx.x;   // 0..47
    int s = threadIdx.x;  // 0..63
    float* dst = PW + (size_t)(s * 48 + o) * 64;
    float w0[4] = {0.f, 0.f, 0.f, 0.f};
    float w1[4] = {0.f, 0.f, 0.f, 0.f};
#pragma unroll
    for (int t = 0; t < 12; ++t) {
#pragma unroll
        for (int c = 0; c < 4; ++c) {
            int wi = ((o * 12 + t) * 4 + c) * 64 + s;
            float ws = w_s[wi];
            float wt = w_t[wi];
            dst[t * 4 + c] = ws;
            float d = wt - ws;
            w0[c] += d;
            w1[c] += (float)t * d;
        }
    }
#pragma unroll
    for (int c = 0; c < 4; ++c) {
        dst[48 + c] = w0[c];
        dst[52 + c] = w1[c];
    }
    dst[56] = b_s[o * 64 + s] + b_t[o * 64 + s];
#pragma unroll
    for (int k = 57; k < 64; ++k) dst[k] = 0.f;
}

// ---- pack2: rearrange PW into exact per-lane B-fragment order (f16):
// PWF[((cls*12+to)*2+ks)*64 + L] = 16B = B[k=ks*32+quad*8+j][n=L&15] for j=0..7.
__global__ __launch_bounds__(64) void pack_frags(const float* __restrict__ PW,
                                                 float4* __restrict__ PWF) {
    int blk = blockIdx.x;  // cls*12 + to, 192 blocks
    int cls = blk / 12;
    int to = blk % 12;
    int L = threadIdx.x;
    int n16 = L & 15, quad = L >> 4;
    int c = n16 >> 2, r = n16 & 3;
    int o = to * 4 + c;
    int rh = cls >> 2, rw = cls & 3;
    int s = (rh + 4 * (r >> 1)) * 8 + (rw + 4 * (r & 1));
    const float* src = PW + (size_t)(s * 48 + o) * 64;
#pragma unroll
    for (int ks = 0; ks < 2; ++ks) {
        F4F16 u;
#pragma unroll
        for (int j = 0; j < 8; ++j) {
            int k = ks * 32 + quad * 8 + j;
            u.h8[j] = (_Float16)src[k];
        }
        PWF[((size_t)blk * 2 + ks) * 64 + L] = u.f4;
    }
}

// ---- main: grid 512 = 32 b x 16 cls (2 blocks/CU), 256 threads (4 waves).
__global__ __launch_bounds__(256, 2) void dlinear_mfma(const float* __restrict__ x,
                                                       const float4* __restrict__ PWF,
                                                       float* __restrict__ out) {
    __shared__ float4 As[256 * 9];  // 256 pixel rows x 144 B (64 f16 + pad 8)
    int tid = threadIdx.x;
    int wv = tid >> 6, L = tid & 63;
    int cls = blockIdx.x & 15;
    int bb = blockIdx.x >> 4;
    int rh = cls >> 2, rw = cls & 3;

    // B fragments persistent in VGPRs (24 coalesced 16B loads, L2-hot).
    f16x8 bf[12][2];
#pragma unroll
    for (int to = 0; to < 12; ++to)
#pragma unroll
        for (int ks = 0; ks < 2; ++ks) {
            F4F16 u;
            u.f4 = PWF[((size_t)(cls * 12 + to) * 2 + ks) * 64 + L];
            bf[to][ks] = u.h8;
        }

    // Phase 1: per-pixel X -> LDS row (thread = pixel p = hh*16+ww).
    int hh = tid >> 4, ww = tid & 15;
    int h = 4 * hh + rh, wcol0 = 4 * ww + rw;
    const float4* xb = (const float4*)x + (size_t)bb * 12 * 4096 + h * 64 + wcol0;

    h2 X2[32] __attribute__((aligned(16)));
    {
        float sx = 0.f, sy = 0.f, sz = 0.f, sw = 0.f;
        float4 first, last;
#pragma unroll
        for (int t = 0; t < 12; ++t) {
            float4 v = xb[t * 4096];
            if (t == 0) first = v;
            if (t == 11) last = v;
            h2 a, b;
            a[0] = (_Float16)v.x; a[1] = (_Float16)v.y;
            b[0] = (_Float16)v.z; b[1] = (_Float16)v.w;
            X2[2 * t] = a;
            X2[2 * t + 1] = b;
            sx += v.x; sy += v.y; sz += v.z; sw += v.w;
        }
        const float inv25 = 1.f / 25.f;
        float A0 = (sx + 12.f * first.x + last.x) * inv25;
        float A1 = (sy + 12.f * first.y + last.y) * inv25;
        float A2 = (sz + 12.f * first.z + last.z) * inv25;
        float A3 = (sw + 12.f * first.w + last.w) * inv25;
        float D0 = (last.x - first.x) * inv25;
        float D1 = (last.y - first.y) * inv25;
        float D2 = (last.z - first.z) * inv25;
        float D3 = (last.w - first.w) * inv25;
        h2 t0, t1, t2, t3, t4, z;
        t0[0] = (_Float16)A0; t0[1] = (_Float16)A1;
        t1[0] = (_Float16)A2; t1[1] = (_Float16)A3;
        t2[0] = (_Float16)D0; t2[1] = (_Float16)D1;
        t3[0] = (_Float16)D2; t3[1] = (_Float16)D3;
        t4[0] = (_Float16)1.f; t4[1] = (_Float16)0.f;
        z[0] = (_Float16)0.f; z[1] = (_Float16)0.f;
        X2[24] = t0; X2[25] = t1; X2[26] = t2; X2[27] = t3;
        X2[28] = t4; X2[29] = z; X2[30] = z; X2[31] = z;
    }
#pragma unroll
    for (int j = 0; j < 8; ++j) As[tid * 9 + j] = ((float4*)X2)[j];
    __syncthreads();

    // Phase 2: A fragments for this wave's 4 m-tiles (pixels wv*64+mt*16+m).
    int quad = L >> 4, mlane = L & 15;
    f16x8 af[4][2];
#pragma unroll
    for (int mt = 0; mt < 4; ++mt) {
        int p = wv * 64 + mt * 16 + mlane;
#pragma unroll
        for (int ks = 0; ks < 2; ++ks) {
            F4F16 u;
            u.f4 = As[p * 9 + ks * 4 + quad];
            af[mt][ks] = u.h8;
        }
    }

    // Phase 3: MFMA + masked combo butterfly + scatter store.
    // D layout: n = lane&15 (c = n>>2, combo r = n&3); m = quad*4 + reg.
    int r = L & 3, cch = (L >> 2) & 3;
    bool dj = (r & 1) != 0;
    bool di = (r & 2) != 0;
    float* outb = out + (size_t)bb * 12 * 16384;

#pragma unroll
    for (int to = 0; to < 12; ++to) {
#pragma unroll
        for (int mt = 0; mt < 4; ++mt) {
            f32x4 d = {0.f, 0.f, 0.f, 0.f};
            d = __builtin_amdgcn_mfma_f32_16x16x32_f16(af[mt][0], bf[to][0], d, 0, 0, 0);
            d = __builtin_amdgcn_mfma_f32_16x16x32_f16(af[mt][1], bf[to][1], d, 0, 0, 0);
            int hq = wv * 4 + mt;  // hh of this m-tile (wave-uniform)
            bool okh = di ? (hq >= 1) : (hq <= 14);
            float s_[4];
#pragma unroll
            for (int reg = 0; reg < 4; ++reg) {
                int mm = quad * 4 + reg;
                bool okw = dj ? (mm >= 1) : (mm <= 14);
                float v = (okh && okw) ? d[reg] : 0.f;
                v += __shfl_xor(v, 1);
                v += __shfl_xor(v, 2);
                s_[reg] = v;  // completed combo-sum for pixel m = quad*4+reg
            }
            // lane r writes pixel mm* = quad*4 + r, channel cch
            float val = (r == 0) ? s_[0] : (r == 1) ? s_[1] : (r == 2) ? s_[2] : s_[3];
            int wc = 16 * quad + 4 * r + rw;
            outb[(size_t)to * 16384 + (4 * hq + rh) * 256 + wc * 4 + cch] = val;
        }
    }
}

extern "C" void kernel_launch(void* const* d_in, const int* in_sizes, int n_in,
                              void* d_out, int out_size, void* d_ws, size_t ws_size,
                              hipStream_t stream) {
    const float* x = (const float*)d_in[0];
    const float* w_s = (const float*)d_in[1];
    const float* b_s = (const float*)d_in[2];
    const float* w_t = (const float*)d_in[3];
    const float* b_t = (const float*)d_in[4];
    float* out = (float*)d_out;
    float* PW = (float*)d_ws;                               // 48*64*64*4   = 786432 B
    float4* PWF = (float4*)((char*)d_ws + 48 * 64 * 64 * 4); // 192*2*64*16 = 393216 B

    pack_weights<<<48, 64, 0, stream>>>(w_s, b_s, w_t, b_t, PW);
    pack_frags<<<192, 64, 0, stream>>>(PW, PWF);
    dlinear_mfma<<<32 * 16, 256, 0, stream>>>(x, PWF, out);
}